// Round 6
// baseline (1284.413 us; speedup 1.0000x reference)
//
#include <hip/hip_runtime.h>

// Problem constants (fixed by reference)
constexpr int N_NEURONS  = 131072;
constexpr int X_ELEMS    = 4 * 131072 * 32;   // 16,777,216
constexpr int X4         = X_ELEMS / 4;       // 4,194,304 float4
constexpr int STATES_OFF = X_ELEMS;           // states start after x in d_out
constexpr int X4_PER_THR = X4 / N_NEURONS;    // 32 float4 per thread

// Fast tanh: t = 1 - 2/(e^{2|x|}+1), sign restored. Overflow-clean.
__device__ __forceinline__ float fast_tanh(float x) {
  float a = fabsf(x);
  float e = __expf(2.0f * a);
  float t = 1.0f - __fdividef(2.0f, e + 1.0f);
  return copysignf(t, x);
}

// ---------------------------------------------------------------------------
// R10: fused kernel + T14 software pipeline for the x-path.
//
// R9 post-mortem: fusion won wall-clock (total 278->246; the separate tanh
// kernel cost ~85us) but the fused kernel regressed vs states-alone
// (133->186us) and VALUBusy collapsed 62->33%: the 8 x-loads per layer were
// consumed by tanh IMMEDIATELY after issue -> full HBM-latency vmcnt stall
// at 2 waves/SIMD, with the f64 cover sitting AFTER the consume in program
// order. Classic T14 fix (issue-early / consume-late):
//   * pB half (4 float4) issued BEFORE the encoder, consumed after decoder.
//   * pA half for layer L+1 issued BEFORE the decoder, consumed after the
//     NEXT layer's encoder. Every load gets >=4K cycles of f64 cover.
//   * asm volatile("" ::: "memory") before each consume block pins the
//     loads above it (global vs LDS don't alias, nothing else stops hipcc
//     sinking loads to their use point).
// In-flight: pA+pB = 32 VGPR; peak live ~175. Falsifier: WRITE_SIZE above
// ~85MB means the allocator spilled -> next step is ws-in-LDS role swap.
// Everything f64 (pinned by R7's fail); decisions identical to R8/R9.
// ---------------------------------------------------------------------------

__device__ double g_wenc_t[32 * 16];  // TRANSPOSED: [k][c]
__device__ double g_wdec[32 * 16];    // [state][c] row-major, as given
__device__ double g_benc[16];
__device__ double g_bdec[32];

__global__ __launch_bounds__(256) void convert_weights_kernel(
    const float* __restrict__ Wenc, const float* __restrict__ benc,
    const float* __restrict__ Wdec, const float* __restrict__ bdec) {
  const int t = threadIdx.x;
  #pragma unroll
  for (int i = t; i < 512; i += 256) {
    const int k = i >> 4, c = i & 15;
    g_wenc_t[i] = (double)Wenc[c * 32 + k];   // transpose
    g_wdec[i]   = (double)Wdec[i];
  }
  if (t < 16)              g_benc[t]      = (double)benc[t];
  if (t >= 64 && t < 96)   g_bdec[t - 64] = (double)bdec[t - 64];
}

__global__ __launch_bounds__(256)
__attribute__((amdgpu_waves_per_eu(2, 2)))
void enn_fused_kernel(const float* __restrict__ x,
                      const float* __restrict__ ns,
                      float* __restrict__ out) {
  // 32 states x 256 threads, f64 = 64 KB. Column-per-thread: conflict-free,
  // no __syncthreads (each thread touches only its own column). The 64KB
  // also caps the backend occupancy model at 2 blocks/CU, which is what
  // unlocks the bigger VGPR budget (R8 lesson).
  __shared__ double s_lds[32][256];

  const int tid = threadIdx.x;
  const int n   = blockIdx.x * 256 + tid;   // one neuron per thread

  const float4* src = reinterpret_cast<const float4*>(ns) + (size_t)n * 8;
  #pragma unroll
  for (int j = 0; j < 8; ++j) {
    float4 v = src[j];
    s_lds[4 * j + 0][tid] = (double)v.x;
    s_lds[4 * j + 1][tid] = (double)v.y;
    s_lds[4 * j + 2][tid] = (double)v.z;
    s_lds[4 * j + 3][tid] = (double)v.w;
  }

  double ws[32];
  #pragma unroll
  for (int i = 0; i < 32; ++i) ws[i] = 0.0;

  // x-path: this thread's 32 float4, coalesced per 256-thread chunk.
  const float4* xb = reinterpret_cast<const float4*>(x);
  float4*       ob = reinterpret_cast<float4*>(out);
  const size_t xbase = (size_t)blockIdx.x * (256 * X4_PER_THR) + tid;

  // Prologue: prefetch layer-0 first half (covered by LDS fill + recurrence
  // + encoder before first consume).
  float4 pA[4], pB[4];
  #pragma unroll
  for (int j = 0; j < 4; ++j) pA[j] = xb[xbase + (size_t)j * 256];

  double nrm = 0.0;
  double thr = 0.01;    // layer-0: sparsity only (deferred kth = 0)
  double kth = 0.0;
  #pragma unroll 1      // rolled: layer body fits I-cache
  for (int layer = 0; layer < 4; ++layer) {
    nrm = nrm * 0.7 + 1.0;            // w.sum(): 1, 1.7, 2.19, 2.533
    const double inv = 1.0 / nrm;

    // Deferred top-k + sparsity (f64), decay, recency recurrence.
    #pragma unroll
    for (int k = 0; k < 32; ++k) {
      double v = s_lds[k][tid];
      v = (fabs(v) >= thr) ? v : 0.0;
      ws[k] = ws[k] * 0.7 + v * 0.9;
    }

    // Prefetch second half of this layer's x-chunks (consumed after the
    // decoder: >= decoder + tanh-A of cover).
    #pragma unroll
    for (int j = 0; j < 4; ++j)
      pB[j] = xb[xbase + (size_t)(layer * 8 + 4 + j) * 256];

    // Encoder: h = relu((ws @ Wenc^T)*inv + benc), f64 acc; transposed
    // weights -> each k-step reads 16 contiguous wave-uniform doubles.
    double hd[16];
    #pragma unroll
    for (int c = 0; c < 16; ++c) hd[c] = 0.0;
    #pragma unroll
    for (int k = 0; k < 32; ++k) {
      double wk = ws[k];
      #pragma unroll
      for (int c = 0; c < 16; ++c)
        hd[c] = fma(wk, g_wenc_t[k * 16 + c], hd[c]);
    }
    #pragma unroll
    for (int c = 0; c < 16; ++c)
      hd[c] = fmax(fma(hd[c], inv, g_benc[c]), 0.0);

    // Consume pA (loads issued >= one full f64 block ago). The memory
    // clobber stops hipcc sinking those loads to this point.
    asm volatile("" ::: "memory");
    #pragma unroll
    for (int j = 0; j < 4; ++j) {
      float4 v = pA[j];
      #pragma unroll
      for (int r = 0; r < 4; ++r) {   // tanh applied once per ref layer
        v.x = fast_tanh(v.x); v.y = fast_tanh(v.y);
        v.z = fast_tanh(v.z); v.w = fast_tanh(v.w);
      }
      ob[xbase + (size_t)(layer * 8 + j) * 256] = v;
    }

    // Prefetch next layer's first half (consumed after NEXT encoder).
    if (layer < 3) {
      #pragma unroll
      for (int j = 0; j < 4; ++j)
        pA[j] = xb[xbase + (size_t)((layer + 1) * 8 + j) * 256];
    }

    // Decoder (f64), importance threshold 0.05, write to LDS, dual
    // interleaved top-8 ladders (even/odd i) for ILP on the serial chain.
    double ta[8], tb[8];
    #pragma unroll
    for (int k = 0; k < 8; ++k) { ta[k] = 0.0; tb[k] = 0.0; }
    #pragma unroll
    for (int i = 0; i < 32; ++i) {
      double acc = g_bdec[i];
      #pragma unroll
      for (int c = 0; c < 16; ++c)
        acc = fma(hd[c], g_wdec[i * 16 + c], acc);
      double r = (fabs(acc) >= 0.05) ? acc : 0.0;
      s_lds[i][tid] = r;
      double v = fabs(r);
      if ((i & 1) == 0) {
        #pragma unroll
        for (int k = 0; k < 8; ++k) {
          double hi = fmax(ta[k], v);
          v = fmin(ta[k], v);
          ta[k] = hi;
        }
      } else {
        #pragma unroll
        for (int k = 0; k < 8; ++k) {
          double hi = fmax(tb[k], v);
          v = fmin(tb[k], v);
          tb[k] = hi;
        }
      }
    }
    // top-8 of union of two sorted-desc 8-lists: c[j]=max(a[j],b[7-j]);
    // kth (8th largest overall) = min over c[].
    double m0 = fmax(ta[0], tb[7]), m1 = fmax(ta[1], tb[6]);
    double m2 = fmax(ta[2], tb[5]), m3 = fmax(ta[3], tb[4]);
    double m4 = fmax(ta[4], tb[3]), m5 = fmax(ta[5], tb[2]);
    double m6 = fmax(ta[6], tb[1]), m7 = fmax(ta[7], tb[0]);
    kth = fmin(fmin(fmin(m0, m1), fmin(m2, m3)),
               fmin(fmin(m4, m5), fmin(m6, m7)));
    thr = fmax(kth, 0.01);        // deferred into next layer's filter

    // Consume pB (issued before the encoder: >= encoder + tanh-A + decoder
    // of cover).
    asm volatile("" ::: "memory");
    #pragma unroll
    for (int j = 0; j < 4; ++j) {
      float4 v = pB[j];
      #pragma unroll
      for (int r = 0; r < 4; ++r) {
        v.x = fast_tanh(v.x); v.y = fast_tanh(v.y);
        v.z = fast_tanh(v.z); v.w = fast_tanh(v.w);
      }
      ob[xbase + (size_t)(layer * 8 + 4 + j) * 256] = v;
    }
  }

  // Final deferred top-k filter (layer 3's kth), convert, store.
  float4* dst = reinterpret_cast<float4*>(out + STATES_OFF) + (size_t)n * 8;
  #pragma unroll
  for (int j = 0; j < 8; ++j) {
    float r[4];
    #pragma unroll
    for (int q = 0; q < 4; ++q) {
      double v = s_lds[4 * j + q][tid];
      r[q] = (float)((fabs(v) >= kth) ? v : 0.0);
    }
    dst[j] = make_float4(r[0], r[1], r[2], r[3]);
  }
}

extern "C" void kernel_launch(void* const* d_in, const int* in_sizes, int n_in,
                              void* d_out, int out_size, void* d_ws, size_t ws_size,
                              hipStream_t stream) {
  const float* x    = (const float*)d_in[0];
  const float* ns   = (const float*)d_in[1];
  const float* Wenc = (const float*)d_in[2];
  const float* benc = (const float*)d_in[3];
  const float* Wdec = (const float*)d_in[4];
  const float* bdec = (const float*)d_in[5];
  float* out = (float*)d_out;

  convert_weights_kernel<<<1, 256, 0, stream>>>(Wenc, benc, Wdec, bdec);
  enn_fused_kernel<<<N_NEURONS / 256, 256, 0, stream>>>(x, ns, out);
}

// Round 9
// 229.946 us; speedup vs baseline: 5.5857x; 5.5857x over previous
//
#include <hip/hip_runtime.h>

// Problem constants (fixed by reference)
constexpr int N_NEURONS  = 131072;
constexpr int X_ELEMS    = 4 * 131072 * 32;   // 16,777,216
constexpr int X4         = X_ELEMS / 4;       // 4,194,304 float4
constexpr int STATES_OFF = X_ELEMS;           // states start after x in d_out

// Fast tanh: t = 1 - 2/(e^{2|x|}+1), sign restored. Overflow-clean.
__device__ __forceinline__ float fast_tanh(float x) {
  float a = fabsf(x);
  float e = __expf(2.0f * a);
  float t = 1.0f - __fdividef(2.0f, e + 1.0f);
  return copysignf(t, x);
}

// ---------------------------------------------------------------------------
// R12: WAVE-SPECIALIZED fused kernel. Overlap via TLP, not instruction
// scheduling.
//
// R10 post-mortem: memory-clobber fences -> 3 GB spill. R11 post-mortem:
// bare asm volatile("") fences -> graph-replay-dependent corruption of the
// x output (post-timing absmax 0.5664 = max|tanh^4|, i.e. x-region zeros):
// operand-less inline asm around in-flight global loads is unsafe with
// hipcc's scheduler/waitcnt passes. Verdict: NO source-level instruction
// pipelining; no inline asm.
//
// Instead use the hardware's own overlap (m114: waves on one CU overlap
// fully, time = max not sum): 512-thread blocks, 8 waves.
//   waves 0-3 (tid<256): the R8/R9 states path, byte-identical decisions.
//   waves 4-7: streaming tanh over the block's 8192 float4 x-chunk.
// Per SIMD: 2 f64-waves + 2 tanh-waves resident; tanh (~14us of work)
// issues into the f64 waves' stall cycles. Branch is wave-uniform; no
// __syncthreads (each states thread owns its LDS column); x-region and
// states-region writes disjoint.
// Occupancy: 64KB LDS -> 2 blocks/CU -> 16 waves/CU -> 4 waves/SIMD;
// 16 x 128 VGPR = 2048 = full file. States path ~108 VGPR (R9) fits the
// allocator's immovable 128 tier.
// ---------------------------------------------------------------------------

__device__ double g_wenc_t[32 * 16];  // TRANSPOSED: [k][c]
__device__ double g_wdec[32 * 16];    // [state][c] row-major, as given
__device__ double g_benc[16];
__device__ double g_bdec[32];

__global__ __launch_bounds__(256) void convert_weights_kernel(
    const float* __restrict__ Wenc, const float* __restrict__ benc,
    const float* __restrict__ Wdec, const float* __restrict__ bdec) {
  const int t = threadIdx.x;
  #pragma unroll
  for (int i = t; i < 512; i += 256) {
    const int k = i >> 4, c = i & 15;
    g_wenc_t[i] = (double)Wenc[c * 32 + k];   // transpose
    g_wdec[i]   = (double)Wdec[i];
  }
  if (t < 16)              g_benc[t]      = (double)benc[t];
  if (t >= 64 && t < 96)   g_bdec[t - 64] = (double)bdec[t - 64];
}

__global__ __launch_bounds__(512)
void enn_fused_kernel(const float* __restrict__ x,
                      const float* __restrict__ ns,
                      float* __restrict__ out) {
  // 32 states x 256 threads, f64 = 64 KB. Column-per-thread: conflict-free.
  __shared__ double s_lds[32][256];

  const int tid = threadIdx.x;

  if (tid < 256) {
    // =================== STATES PATH (waves 0-3) =========================
    const int n = blockIdx.x * 256 + tid;   // one neuron per thread

    const float4* src = reinterpret_cast<const float4*>(ns) + (size_t)n * 8;
    #pragma unroll
    for (int j = 0; j < 8; ++j) {
      float4 v = src[j];
      s_lds[4 * j + 0][tid] = (double)v.x;
      s_lds[4 * j + 1][tid] = (double)v.y;
      s_lds[4 * j + 2][tid] = (double)v.z;
      s_lds[4 * j + 3][tid] = (double)v.w;
    }

    double ws[32];
    #pragma unroll
    for (int i = 0; i < 32; ++i) ws[i] = 0.0;

    double nrm = 0.0;
    double thr = 0.01;    // layer-0: sparsity only (deferred kth = 0)
    double kth = 0.0;
    #pragma unroll 1      // rolled: layer body fits I-cache
    for (int layer = 0; layer < 4; ++layer) {
      nrm = nrm * 0.7 + 1.0;            // w.sum(): 1, 1.7, 2.19, 2.533
      const double inv = 1.0 / nrm;

      // Deferred top-k + sparsity (f64), decay, recency recurrence.
      #pragma unroll
      for (int k = 0; k < 32; ++k) {
        double v = s_lds[k][tid];
        v = (fabs(v) >= thr) ? v : 0.0;
        ws[k] = ws[k] * 0.7 + v * 0.9;
      }

      // Encoder: h = relu((ws @ Wenc^T)*inv + benc), f64 acc; transposed
      // weights -> each k-step reads 16 contiguous wave-uniform doubles.
      double hd[16];
      #pragma unroll
      for (int c = 0; c < 16; ++c) hd[c] = 0.0;
      #pragma unroll
      for (int k = 0; k < 32; ++k) {
        double wk = ws[k];
        #pragma unroll
        for (int c = 0; c < 16; ++c)
          hd[c] = fma(wk, g_wenc_t[k * 16 + c], hd[c]);
      }
      #pragma unroll
      for (int c = 0; c < 16; ++c)
        hd[c] = fmax(fma(hd[c], inv, g_benc[c]), 0.0);

      // Decoder (f64), importance threshold 0.05, write to LDS, dual
      // interleaved top-8 ladders (even/odd i) for ILP on the serial chain.
      double ta[8], tb[8];
      #pragma unroll
      for (int k = 0; k < 8; ++k) { ta[k] = 0.0; tb[k] = 0.0; }
      #pragma unroll
      for (int i = 0; i < 32; ++i) {
        double acc = g_bdec[i];
        #pragma unroll
        for (int c = 0; c < 16; ++c)
          acc = fma(hd[c], g_wdec[i * 16 + c], acc);
        double r = (fabs(acc) >= 0.05) ? acc : 0.0;
        s_lds[i][tid] = r;
        double v = fabs(r);
        if ((i & 1) == 0) {
          #pragma unroll
          for (int k = 0; k < 8; ++k) {
            double hi = fmax(ta[k], v);
            v = fmin(ta[k], v);
            ta[k] = hi;
          }
        } else {
          #pragma unroll
          for (int k = 0; k < 8; ++k) {
            double hi = fmax(tb[k], v);
            v = fmin(tb[k], v);
            tb[k] = hi;
          }
        }
      }
      // top-8 of union of two sorted-desc 8-lists: c[j]=max(a[j],b[7-j]);
      // kth (8th largest overall) = min over c[].
      double m0 = fmax(ta[0], tb[7]), m1 = fmax(ta[1], tb[6]);
      double m2 = fmax(ta[2], tb[5]), m3 = fmax(ta[3], tb[4]);
      double m4 = fmax(ta[4], tb[3]), m5 = fmax(ta[5], tb[2]);
      double m6 = fmax(ta[6], tb[1]), m7 = fmax(ta[7], tb[0]);
      kth = fmin(fmin(fmin(m0, m1), fmin(m2, m3)),
                 fmin(fmin(m4, m5), fmin(m6, m7)));
      thr = fmax(kth, 0.01);        // deferred into next layer's filter
    }

    // Final deferred top-k filter (layer 3's kth), convert, store.
    float4* dst = reinterpret_cast<float4*>(out + STATES_OFF) + (size_t)n * 8;
    #pragma unroll
    for (int j = 0; j < 8; ++j) {
      float r[4];
      #pragma unroll
      for (int q = 0; q < 4; ++q) {
        double v = s_lds[4 * j + q][tid];
        r[q] = (float)((fabs(v) >= kth) ? v : 0.0);
      }
      dst[j] = make_float4(r[0], r[1], r[2], r[3]);
    }
  } else {
    // =================== TANH PATH (waves 4-7) ===========================
    // This block's x-chunk: 8192 float4, 32 per tanh-thread, coalesced.
    // These waves run CONCURRENTLY with the f64 waves on the same SIMDs;
    // their loads/f32 ops fill the f64 waves' stall cycles (m114 overlap).
    const int xt = tid - 256;
    const float4* xb = reinterpret_cast<const float4*>(x);
    float4*       ob = reinterpret_cast<float4*>(out);
    const size_t base = (size_t)blockIdx.x * 8192 + xt;

    #pragma unroll 1
    for (int j = 0; j < 32; j += 4) {
      // 4 loads issued together (straight-line) -> 4x memory-level
      // parallelism; no fences, compiler handles waitcnt placement.
      float4 v0 = xb[base + (size_t)(j + 0) * 256];
      float4 v1 = xb[base + (size_t)(j + 1) * 256];
      float4 v2 = xb[base + (size_t)(j + 2) * 256];
      float4 v3 = xb[base + (size_t)(j + 3) * 256];
      #pragma unroll
      for (int r = 0; r < 4; ++r) {   // tanh applied once per ref layer
        v0.x = fast_tanh(v0.x); v0.y = fast_tanh(v0.y);
        v0.z = fast_tanh(v0.z); v0.w = fast_tanh(v0.w);
        v1.x = fast_tanh(v1.x); v1.y = fast_tanh(v1.y);
        v1.z = fast_tanh(v1.z); v1.w = fast_tanh(v1.w);
        v2.x = fast_tanh(v2.x); v2.y = fast_tanh(v2.y);
        v2.z = fast_tanh(v2.z); v2.w = fast_tanh(v2.w);
        v3.x = fast_tanh(v3.x); v3.y = fast_tanh(v3.y);
        v3.z = fast_tanh(v3.z); v3.w = fast_tanh(v3.w);
      }
      ob[base + (size_t)(j + 0) * 256] = v0;
      ob[base + (size_t)(j + 1) * 256] = v1;
      ob[base + (size_t)(j + 2) * 256] = v2;
      ob[base + (size_t)(j + 3) * 256] = v3;
    }
  }
}

extern "C" void kernel_launch(void* const* d_in, const int* in_sizes, int n_in,
                              void* d_out, int out_size, void* d_ws, size_t ws_size,
                              hipStream_t stream) {
  const float* x    = (const float*)d_in[0];
  const float* ns   = (const float*)d_in[1];
  const float* Wenc = (const float*)d_in[2];
  const float* benc = (const float*)d_in[3];
  const float* Wdec = (const float*)d_in[4];
  const float* bdec = (const float*)d_in[5];
  float* out = (float*)d_out;

  convert_weights_kernel<<<1, 256, 0, stream>>>(Wenc, benc, Wdec, bdec);
  enn_fused_kernel<<<N_NEURONS / 256, 512, 0, stream>>>(x, ns, out);
}

// Round 11
// 193.946 us; speedup vs baseline: 6.6225x; 1.1856x over previous
//
#include <hip/hip_runtime.h>

// Problem constants (fixed by reference)
constexpr int N_NEURONS  = 131072;
constexpr int X_ELEMS    = 4 * 131072 * 32;   // 16,777,216
constexpr int X4         = X_ELEMS / 4;       // 4,194,304 float4
constexpr int STATES_OFF = X_ELEMS;           // states start after x in d_out

// Fast tanh: t = 1 - 2/(e^{2|x|}+1), sign restored. Overflow-clean.
__device__ __forceinline__ float fast_tanh(float x) {
  float a = fabsf(x);
  float e = __expf(2.0f * a);
  float t = 1.0f - __fdividef(2.0f, e + 1.0f);
  return copysignf(t, x);
}

// ---------------------------------------------------------------------------
// R13 (resubmitted unchanged after infra failure): R12's wave-specialized
// structure (PROVEN: tanh fully hidden, zero spill, 122.8us) + f64 op-count
// trims. States waves are hard-capped at 2/SIMD (1 neuron/thread forced by
// SGPR scalarization), so the only lever left is fewer DP ops:
//  1. kth via SELECTION NETWORK, not insertion ladder: 4x Batcher sort-8
//     (19 CE) + 2x bitonic half-merge+merge (8+12 CE) + final 2-list kth
//     (15 ops) = 231 f64 ops vs 512. Comparison-exact, same kth.
//  2. u-carry encoder: carry u[c] = E(ws~) across layers; u = 0.7u + E(v).
//     ws[32] (64 VGPR) never materialized -> pays for the network's +16
//     working set. E is linear -> exact modulo f64 assoc (R6 precedent).
//  3. 0.9-fold: ws~ recurrence drops the *0.9; folded into inv9 = 0.9/nrm
//     (one uniform mul per layer).
// Per-layer f64 ops 1840 -> ~1495 (-19%).
// Everything f64 (pinned by R7 fail); threshold semantics identical.
// NO inline asm of any kind (R10/R11 lessons).
// ---------------------------------------------------------------------------

__device__ double g_wenc_t[32 * 16];  // TRANSPOSED: [k][c]
__device__ double g_wdec[32 * 16];    // [state][c] row-major, as given
__device__ double g_benc[16];
__device__ double g_bdec[32];

__global__ __launch_bounds__(256) void convert_weights_kernel(
    const float* __restrict__ Wenc, const float* __restrict__ benc,
    const float* __restrict__ Wdec, const float* __restrict__ bdec) {
  const int t = threadIdx.x;
  #pragma unroll
  for (int i = t; i < 512; i += 256) {
    const int k = i >> 4, c = i & 15;
    g_wenc_t[i] = (double)Wenc[c * 32 + k];   // transpose
    g_wdec[i]   = (double)Wdec[i];
  }
  if (t < 16)              g_benc[t]      = (double)benc[t];
  if (t >= 64 && t < 96)   g_bdec[t - 64] = (double)bdec[t - 64];
}

// Compare-exchange, descending (max lands in a).
__device__ __forceinline__ void ce(double& a, double& b) {
  double hi = fmax(a, b);
  b = fmin(a, b);
  a = hi;
}

// Batcher odd-even mergesort for 8, descending, with |.| folded into the
// first stage (abs is a free input modifier on f64 min/max).
__device__ __forceinline__ void sortnet8_abs(double q[8]) {
  #pragma unroll
  for (int j = 0; j < 8; j += 2) {
    double hi = fmax(fabs(q[j]), fabs(q[j + 1]));
    double lo = fmin(fabs(q[j]), fabs(q[j + 1]));
    q[j] = hi; q[j + 1] = lo;
  }
  ce(q[0], q[2]); ce(q[1], q[3]); ce(q[1], q[2]);
  ce(q[4], q[6]); ce(q[5], q[7]); ce(q[5], q[6]);
  ce(q[0], q[4]); ce(q[1], q[5]); ce(q[2], q[6]); ce(q[3], q[7]);
  ce(q[2], q[4]); ce(q[3], q[5]);
  ce(q[1], q[2]); ce(q[3], q[4]); ce(q[5], q[6]);
}

// Bitonic merger for 8 (input bitonic), descending.
__device__ __forceinline__ void bitonic8(double m[8]) {
  ce(m[0], m[4]); ce(m[1], m[5]); ce(m[2], m[6]); ce(m[3], m[7]);
  ce(m[0], m[2]); ce(m[1], m[3]); ce(m[4], m[6]); ce(m[5], m[7]);
  ce(m[0], m[1]); ce(m[2], m[3]); ce(m[4], m[5]); ce(m[6], m[7]);
}

__global__ __launch_bounds__(512)
void enn_fused_kernel(const float* __restrict__ x,
                      const float* __restrict__ ns,
                      float* __restrict__ out) {
  // 32 states x 256 threads, f64 = 64 KB. Column-per-thread: conflict-free;
  // no __syncthreads (each states thread owns its column).
  __shared__ double s_lds[32][256];

  const int tid = threadIdx.x;

  if (tid < 256) {
    // =================== STATES PATH (waves 0-3) =========================
    const int n = blockIdx.x * 256 + tid;   // one neuron per thread

    const float4* src = reinterpret_cast<const float4*>(ns) + (size_t)n * 8;
    #pragma unroll
    for (int j = 0; j < 8; ++j) {
      float4 v = src[j];
      s_lds[4 * j + 0][tid] = (double)v.x;
      s_lds[4 * j + 1][tid] = (double)v.y;
      s_lds[4 * j + 2][tid] = (double)v.z;
      s_lds[4 * j + 3][tid] = (double)v.w;
    }

    // u[c] = Encoder(ws~) carried across layers (ws~ never materialized).
    double u[16];
    #pragma unroll
    for (int c = 0; c < 16; ++c) u[c] = 0.0;

    double nrm = 0.0;
    double thr = 0.01;    // layer-0: sparsity only (deferred kth = 0)
    double kth = 0.0;
    #pragma unroll 1      // rolled: layer body fits I-cache
    for (int layer = 0; layer < 4; ++layer) {
      nrm = nrm * 0.7 + 1.0;            // w.sum(): 1, 1.7, 2.19, 2.533
      const double inv9 = 0.9 / nrm;    // 0.9 decay folded with 1/w.sum()

      // u = 0.7*u + E(v), v = deferred-filtered s (|s| >= max(kth,0.01)).
      #pragma unroll
      for (int c = 0; c < 16; ++c) u[c] = u[c] * 0.7;
      #pragma unroll
      for (int k = 0; k < 32; ++k) {
        double v = s_lds[k][tid];
        v = (fabs(v) >= thr) ? v : 0.0;
        #pragma unroll
        for (int c = 0; c < 16; ++c)
          u[c] = fma(v, g_wenc_t[k * 16 + c], u[c]);
      }

      // h = relu(u*inv9 + benc)
      double hd[16];
      #pragma unroll
      for (int c = 0; c < 16; ++c)
        hd[c] = fmax(fma(u[c], inv9, g_benc[c]), 0.0);

      // Decoder in 4 chunks of 8; kth via selection network.
      double qa[8], qb[8], A[8], B[8];
      #pragma unroll
      for (int half = 0; half < 2; ++half) {
        #pragma unroll
        for (int g = 0; g < 2; ++g) {
          double* q = g ? qb : qa;
          const int base = half * 16 + g * 8;
          #pragma unroll
          for (int ii = 0; ii < 8; ++ii) {
            const int i = base + ii;
            double acc = g_bdec[i];
            #pragma unroll
            for (int c = 0; c < 16; ++c)
              acc = fma(hd[c], g_wdec[i * 16 + c], acc);
            double r = (fabs(acc) >= 0.05) ? acc : 0.0;
            s_lds[i][tid] = r;
            q[ii] = r;
          }
          if (g) sortnet8_abs(qb); else sortnet8_abs(qa);
        }
        // top-8 of 16 = {max(qa[j], qb[7-j])} (bitonic), then sort.
        double* T = half ? B : A;
        #pragma unroll
        for (int j = 0; j < 8; ++j) T[j] = fmax(qa[j], qb[7 - j]);
        if (half) bitonic8(B); else bitonic8(A);
      }
      // kth (8th largest of 32) from two sorted-desc 8-lists.
      double m[8];
      #pragma unroll
      for (int j = 0; j < 8; ++j) m[j] = fmax(A[j], B[7 - j]);
      kth = fmin(fmin(fmin(m[0], m[1]), fmin(m[2], m[3])),
                 fmin(fmin(m[4], m[5]), fmin(m[6], m[7])));
      thr = fmax(kth, 0.01);        // deferred into next layer's filter
    }

    // Final deferred top-k filter (layer 3's kth), convert, store.
    float4* dst = reinterpret_cast<float4*>(out + STATES_OFF) + (size_t)n * 8;
    #pragma unroll
    for (int j = 0; j < 8; ++j) {
      float r[4];
      #pragma unroll
      for (int q = 0; q < 4; ++q) {
        double v = s_lds[4 * j + q][tid];
        r[q] = (float)((fabs(v) >= kth) ? v : 0.0);
      }
      dst[j] = make_float4(r[0], r[1], r[2], r[3]);
    }
  } else {
    // =================== TANH PATH (waves 4-7) ===========================
    // Unchanged from R12 (proven hidden under the f64 waves, m114 overlap).
    const int xt = tid - 256;
    const float4* xb = reinterpret_cast<const float4*>(x);
    float4*       ob = reinterpret_cast<float4*>(out);
    const size_t base = (size_t)blockIdx.x * 8192 + xt;

    #pragma unroll 1
    for (int j = 0; j < 32; j += 4) {
      float4 v0 = xb[base + (size_t)(j + 0) * 256];
      float4 v1 = xb[base + (size_t)(j + 1) * 256];
      float4 v2 = xb[base + (size_t)(j + 2) * 256];
      float4 v3 = xb[base + (size_t)(j + 3) * 256];
      #pragma unroll
      for (int r = 0; r < 4; ++r) {   // tanh applied once per ref layer
        v0.x = fast_tanh(v0.x); v0.y = fast_tanh(v0.y);
        v0.z = fast_tanh(v0.z); v0.w = fast_tanh(v0.w);
        v1.x = fast_tanh(v1.x); v1.y = fast_tanh(v1.y);
        v1.z = fast_tanh(v1.z); v1.w = fast_tanh(v1.w);
        v2.x = fast_tanh(v2.x); v2.y = fast_tanh(v2.y);
        v2.z = fast_tanh(v2.z); v2.w = fast_tanh(v2.w);
        v3.x = fast_tanh(v3.x); v3.y = fast_tanh(v3.y);
        v3.z = fast_tanh(v3.z); v3.w = fast_tanh(v3.w);
      }
      ob[base + (size_t)(j + 0) * 256] = v0;
      ob[base + (size_t)(j + 1) * 256] = v1;
      ob[base + (size_t)(j + 2) * 256] = v2;
      ob[base + (size_t)(j + 3) * 256] = v3;
    }
  }
}

extern "C" void kernel_launch(void* const* d_in, const int* in_sizes, int n_in,
                              void* d_out, int out_size, void* d_ws, size_t ws_size,
                              hipStream_t stream) {
  const float* x    = (const float*)d_in[0];
  const float* ns   = (const float*)d_in[1];
  const float* Wenc = (const float*)d_in[2];
  const float* benc = (const float*)d_in[3];
  const float* Wdec = (const float*)d_in[4];
  const float* bdec = (const float*)d_in[5];
  float* out = (float*)d_out;

  convert_weights_kernel<<<1, 256, 0, stream>>>(Wenc, benc, Wdec, bdec);
  enn_fused_kernel<<<N_NEURONS / 256, 512, 0, stream>>>(x, ns, out);
}